// Round 4
// baseline (941.317 us; speedup 1.0000x reference)
//
#include <hip/hip_runtime.h>

// ---------------------------------------------------------------------------
// Petri_GCN: 3x GCNConv(64->64) + MLP readout (64->32->1) + segment-mean pool
// All fp32 (abs threshold forbids bf16/MFMA; no fp32 MFMA on CDNA4).
// R1: CSR-by-dst (counting sort) + gather instead of atomic scatter.
// R2: readout wave-segmented atomics; gather 4x(16-lane x float4) layout.
// R3: count-only atomic pass (deg computed from CSR rows, no float atomics);
//     Ts = (X@W)*dinv epilogue so CSR stores raw w (int2-packed);
//     gather writes A = dinv[d]*(sum + Ts[d]) + b  (pure write, bias fused).
// ---------------------------------------------------------------------------

__global__ void cnt_kernel(const int* __restrict__ dst,
                           int* __restrict__ cnt, int ne) {
    int e = blockIdx.x * blockDim.x + threadIdx.x;
    if (e < ne) atomicAdd(&cnt[dst[e]], 1);
}

// --- 3-pass exclusive scan of cnt[] -> row_ptr[] ---------------------------
#define SCAN_B 256
__global__ void scan1_kernel(const int* __restrict__ cnt,
                             int* __restrict__ excl,
                             int* __restrict__ bsum, int n) {
    __shared__ int sh[SCAN_B];
    int i = blockIdx.x * SCAN_B + threadIdx.x;
    int c = (i < n) ? cnt[i] : 0;
    sh[threadIdx.x] = c;
    __syncthreads();
    for (int off = 1; off < SCAN_B; off <<= 1) {
        int v = (threadIdx.x >= off) ? sh[threadIdx.x - off] : 0;
        __syncthreads();
        sh[threadIdx.x] += v;
        __syncthreads();
    }
    if (i < n) excl[i] = sh[threadIdx.x] - c;
    if (threadIdx.x == SCAN_B - 1) bsum[blockIdx.x] = sh[threadIdx.x];
}

__global__ void scan2_kernel(int* __restrict__ bsum, int nb) {
    __shared__ int sh[512];
    int t = threadIdx.x;
    int v = (t < nb) ? bsum[t] : 0;
    sh[t] = v;
    __syncthreads();
    for (int off = 1; off < 512; off <<= 1) {
        int u = (t >= off) ? sh[t - off] : 0;
        __syncthreads();
        sh[t] += u;
        __syncthreads();
    }
    if (t < nb) bsum[t] = sh[t] - v;
}

__global__ void scan3_kernel(const int* __restrict__ excl,
                             const int* __restrict__ bsum,
                             int* __restrict__ rptr,
                             int* __restrict__ cursor, int n) {
    int i = blockIdx.x * SCAN_B + threadIdx.x;
    if (i < n) {
        int s = excl[i] + bsum[blockIdx.x];
        rptr[i] = s;
        cursor[i] = s;
    }
}

// Fill CSR with {src, raw_w} packed as int2 (one 8B write per edge).
__global__ void fill_kernel(const int* __restrict__ src,
                            const int* __restrict__ dst,
                            const float* __restrict__ ew,
                            int* __restrict__ cursor,
                            int2* __restrict__ csr, int ne) {
    int e = blockIdx.x * blockDim.x + threadIdx.x;
    if (e >= ne) return;
    int d = dst[e];
    int pos = atomicAdd(&cursor[d], 1);
    int2 v;
    v.x = src[e];
    v.y = __float_as_int(ew[e]);
    csr[pos] = v;
}

// deg[r] = sum of raw w over row r (+1 self-loop); dinv = 1/sqrt(deg).
// 16 lanes per row (4 rows per wave), coalesced row-segment reads.
__global__ void deg_row_kernel(const int2* __restrict__ csr,
                               const int* __restrict__ rptr,
                               const int* __restrict__ cnt,
                               float* __restrict__ dinv, int n) {
    int lane = threadIdx.x & 63;
    int wid  = (blockIdx.x * blockDim.x + threadIdx.x) >> 6;
    int sub  = lane >> 4;
    int k    = lane & 15;
    int r = wid * 4 + sub;
    if (r >= n) return;
    int start = rptr[r];
    int m = cnt[r];
    float s = 0.0f;
    for (int j = k; j < m; j += 16) s += __int_as_float(csr[start + j].y);
#pragma unroll
    for (int off = 1; off < 16; off <<= 1) s += __shfl_xor(s, off);
    if (k == 0) dinv[r] = 1.0f / sqrtf(s + 1.0f);
}

// One wave per row. Lane c holds W[:,c] in 64 VGPRs. X row read as uniform
// float4 broadcasts. Single store: Ts = act(X)@W * dinv[r].
template <bool RELU>
__global__ void gemm_ts_kernel(const float* __restrict__ X,
                               const float* __restrict__ W,
                               const float* __restrict__ dinv,
                               float* __restrict__ Ts, int n) {
    int lane = threadIdx.x & 63;
    int wid  = (blockIdx.x * blockDim.x + threadIdx.x) >> 6;
    int nw   = (gridDim.x * blockDim.x) >> 6;
    float wc[64];
#pragma unroll
    for (int k = 0; k < 64; ++k) wc[k] = W[k * 64 + lane];
    for (int r = wid; r < n; r += nw) {
        const float4* xr = (const float4*)(X + (size_t)r * 64);
        float acc = 0.0f;
#pragma unroll
        for (int k4 = 0; k4 < 16; ++k4) {
            float4 x4 = xr[k4];
            if (RELU) {
                x4.x = fmaxf(x4.x, 0.0f); x4.y = fmaxf(x4.y, 0.0f);
                x4.z = fmaxf(x4.z, 0.0f); x4.w = fmaxf(x4.w, 0.0f);
            }
            acc = fmaf(x4.x, wc[4 * k4 + 0], acc);
            acc = fmaf(x4.y, wc[4 * k4 + 1], acc);
            acc = fmaf(x4.z, wc[4 * k4 + 2], acc);
            acc = fmaf(x4.w, wc[4 * k4 + 3], acc);
        }
        Ts[(size_t)r * 64 + lane] = acc * dinv[r];
    }
}

// One wave per dst row. 4 subgroups of 16 lanes; subgroup handles every 4th
// edge; lane's float4 covers channels 4*cl..4*cl+3. One dwordx4 VMEM instr
// serves 4 edges. A[r] = dinv[r]*(sum + Ts[r]) + b  (pure write).
__global__ void gather_kernel(const int2* __restrict__ csr,
                              const int* __restrict__ rptr,
                              const int* __restrict__ cnt,
                              const float* __restrict__ dinv,
                              const float* __restrict__ b,
                              const float* __restrict__ Ts,
                              float* __restrict__ A, int n) {
    int lane = threadIdx.x & 63;
    int r = (int)(((size_t)blockIdx.x * blockDim.x + threadIdx.x) >> 6);
    if (r >= n) return;
    int sub = lane >> 4;          // 0..3: edge subgroup
    int cl  = lane & 15;          // channel quad
    int start = rptr[r];
    int m = cnt[r];
    float4 a0 = {0.f, 0.f, 0.f, 0.f};
    float4 a1 = {0.f, 0.f, 0.f, 0.f};
    int j = sub;
    for (; j + 4 < m; j += 8) {
        int2 e0 = csr[start + j];
        int2 e1 = csr[start + j + 4];
        float w0 = __int_as_float(e0.y);
        float w1 = __int_as_float(e1.y);
        float4 t0 = *(const float4*)&Ts[(size_t)e0.x * 64 + cl * 4];
        float4 t1 = *(const float4*)&Ts[(size_t)e1.x * 64 + cl * 4];
        a0.x = fmaf(t0.x, w0, a0.x); a0.y = fmaf(t0.y, w0, a0.y);
        a0.z = fmaf(t0.z, w0, a0.z); a0.w = fmaf(t0.w, w0, a0.w);
        a1.x = fmaf(t1.x, w1, a1.x); a1.y = fmaf(t1.y, w1, a1.y);
        a1.z = fmaf(t1.z, w1, a1.z); a1.w = fmaf(t1.w, w1, a1.w);
    }
    if (j < m) {
        int2 e0 = csr[start + j];
        float w0 = __int_as_float(e0.y);
        float4 t0 = *(const float4*)&Ts[(size_t)e0.x * 64 + cl * 4];
        a0.x = fmaf(t0.x, w0, a0.x); a0.y = fmaf(t0.y, w0, a0.y);
        a0.z = fmaf(t0.z, w0, a0.z); a0.w = fmaf(t0.w, w0, a0.w);
    }
    a0.x += a1.x; a0.y += a1.y; a0.z += a1.z; a0.w += a1.w;
#pragma unroll
    for (int off = 16; off < 64; off <<= 1) {
        a0.x += __shfl_xor(a0.x, off);
        a0.y += __shfl_xor(a0.y, off);
        a0.z += __shfl_xor(a0.z, off);
        a0.w += __shfl_xor(a0.w, off);
    }
    if (sub == 0) {
        float dv = dinv[r];
        float4 ts = *(const float4*)&Ts[(size_t)r * 64 + cl * 4];
        float4 bb = *(const float4*)&b[cl * 4];
        float4 o;
        o.x = fmaf(dv, a0.x + ts.x, bb.x);
        o.y = fmaf(dv, a0.y + ts.y, bb.y);
        o.z = fmaf(dv, a0.z + ts.z, bb.z);
        o.w = fmaf(dv, a0.w + ts.w, bb.w);
        *(float4*)&A[(size_t)r * 64 + cl * 4] = o;
    }
}

// Thread per node: sv = relu(h @ Wr0 + br0) @ Wr1 + br1.
// batch is sorted -> wave-segmented suffix reduction, heads do the atomics.
__global__ void readout_kernel(const float* __restrict__ H,
                               const float* __restrict__ Wr0,
                               const float* __restrict__ br0,
                               const float* __restrict__ Wr1,
                               const float* __restrict__ br1,
                               const int* __restrict__ batch,
                               float* __restrict__ gsum,
                               float* __restrict__ gcnt, int n) {
    __shared__ float Ws[64 * 32];
    __shared__ float w1s[32];
    for (int i = threadIdx.x; i < 64 * 32; i += blockDim.x) Ws[i] = Wr0[i];
    if (threadIdx.x < 32) w1s[threadIdx.x] = Wr1[threadIdx.x];
    __syncthreads();
    int r = blockIdx.x * blockDim.x + threadIdx.x;
    int lane = threadIdx.x & 63;
    float sv = 0.0f;
    int g = -1;
    if (r < n) {
        float h[64];
        const float4* hr = (const float4*)(H + (size_t)r * 64);
#pragma unroll
        for (int i = 0; i < 16; ++i) {
            float4 v = hr[i];
            h[4 * i + 0] = v.x; h[4 * i + 1] = v.y;
            h[4 * i + 2] = v.z; h[4 * i + 3] = v.w;
        }
        float ssum = 0.0f;
#pragma unroll 1
        for (int jg = 0; jg < 8; ++jg) {
            float a0 = br0[jg * 4 + 0], a1 = br0[jg * 4 + 1];
            float a2 = br0[jg * 4 + 2], a3 = br0[jg * 4 + 3];
#pragma unroll
            for (int k = 0; k < 64; ++k) {
                const float4 wv = *(const float4*)&Ws[k * 32 + jg * 4];
                a0 = fmaf(h[k], wv.x, a0);
                a1 = fmaf(h[k], wv.y, a1);
                a2 = fmaf(h[k], wv.z, a2);
                a3 = fmaf(h[k], wv.w, a3);
            }
            a0 = fmaxf(a0, 0.0f); a1 = fmaxf(a1, 0.0f);
            a2 = fmaxf(a2, 0.0f); a3 = fmaxf(a3, 0.0f);
            ssum += a0 * w1s[jg * 4 + 0] + a1 * w1s[jg * 4 + 1] +
                    a2 * w1s[jg * 4 + 2] + a3 * w1s[jg * 4 + 3];
        }
        sv = ssum + br1[0];
        g = batch[r];
    }
    float c = (r < n) ? 1.0f : 0.0f;
#pragma unroll
    for (int off = 1; off < 64; off <<= 1) {
        int   og = __shfl_down(g, off);
        float ov = __shfl_down(sv, off);
        float oc = __shfl_down(c, off);
        if ((lane + off) < 64 && og == g) { sv += ov; c += oc; }
    }
    int gprev = __shfl_up(g, 1);
    bool head = (lane == 0) || (gprev != g);
    if (head && g >= 0) {
        atomicAdd(&gsum[g], sv);
        atomicAdd(&gcnt[g], c);
    }
}

__global__ void pool_fin_kernel(const float* __restrict__ gsum,
                                const float* __restrict__ gcnt,
                                float* __restrict__ out, int ng) {
    int g = blockIdx.x * blockDim.x + threadIdx.x;
    if (g < ng) out[g] = gsum[g] / fmaxf(gcnt[g], 1.0f);
}

extern "C" void kernel_launch(void* const* d_in, const int* in_sizes, int n_in,
                              void* d_out, int out_size, void* d_ws, size_t ws_size,
                              hipStream_t stream) {
    const float* x    = (const float*)d_in[0];
    const int*   ei   = (const int*)d_in[1];
    const float* ew   = (const float*)d_in[2];
    const int*   batch= (const int*)d_in[3];
    const float* W0   = (const float*)d_in[4];
    const float* b0   = (const float*)d_in[5];
    const float* W1   = (const float*)d_in[6];
    const float* b1   = (const float*)d_in[7];
    const float* W2   = (const float*)d_in[8];
    const float* b2   = (const float*)d_in[9];
    const float* Wr0  = (const float*)d_in[10];
    const float* br0  = (const float*)d_in[11];
    const float* Wr1  = (const float*)d_in[12];
    const float* br1  = (const float*)d_in[13];
    float* out = (float*)d_out;

    int n  = in_sizes[0] / 64;   // 100000
    int ne = in_sizes[1] / 2;    // 1600000
    int ng = out_size;           // 256
    const int* srcv = ei;
    const int* dstv = ei + ne;

    char* ws = (char*)d_ws;
    size_t off = 0;
    auto alloc = [&](size_t bytes) {
        void* p = ws + off;
        off += (bytes + 255) & ~(size_t)255;
        return p;
    };
    float* Ts     = (float*)alloc((size_t)n * 64 * sizeof(float));
    float* A      = (float*)alloc((size_t)n * 64 * sizeof(float));
    float* dinv   = (float*)alloc((size_t)n * sizeof(float));
    int*   cnt    = (int*)alloc((size_t)n * sizeof(int));
    int*   excl   = (int*)alloc((size_t)n * sizeof(int));
    int*   rptr   = (int*)alloc((size_t)n * sizeof(int));
    int*   cursor = (int*)alloc((size_t)n * sizeof(int));
    int*   bsum   = (int*)alloc(512 * sizeof(int));
    int2*  csr    = (int2*)alloc((size_t)ne * sizeof(int2));
    float* gsum   = (float*)alloc((size_t)ng * sizeof(float));
    float* gcnt   = (float*)alloc((size_t)ng * sizeof(float));
    (void)ws_size;

    int nb = (n + SCAN_B - 1) / SCAN_B;   // 391 <= 512

    hipMemsetAsync(cnt, 0, (size_t)n * sizeof(int), stream);
    hipMemsetAsync(gsum, 0, (size_t)ng * sizeof(float), stream);
    hipMemsetAsync(gcnt, 0, (size_t)ng * sizeof(float), stream);

    cnt_kernel<<<(ne + 255) / 256, 256, 0, stream>>>(dstv, cnt, ne);
    scan1_kernel<<<nb, SCAN_B, 0, stream>>>(cnt, excl, bsum, n);
    scan2_kernel<<<1, 512, 0, stream>>>(bsum, nb);
    scan3_kernel<<<nb, SCAN_B, 0, stream>>>(excl, bsum, rptr, cursor, n);
    fill_kernel<<<(ne + 255) / 256, 256, 0, stream>>>(srcv, dstv, ew, cursor, csr, ne);
    deg_row_kernel<<<(n + 15) / 16, 256, 0, stream>>>(csr, rptr, cnt, dinv, n);

    const int gemm_blocks = 1024;
    unsigned gat_blocks = (unsigned)(((size_t)n * 64 + 255) / 256);

    gemm_ts_kernel<false><<<gemm_blocks, 256, 0, stream>>>(x, W0, dinv, Ts, n);
    gather_kernel<<<gat_blocks, 256, 0, stream>>>(csr, rptr, cnt, dinv, b0, Ts, A, n);

    gemm_ts_kernel<true><<<gemm_blocks, 256, 0, stream>>>(A, W1, dinv, Ts, n);
    gather_kernel<<<gat_blocks, 256, 0, stream>>>(csr, rptr, cnt, dinv, b1, Ts, A, n);

    gemm_ts_kernel<true><<<gemm_blocks, 256, 0, stream>>>(A, W2, dinv, Ts, n);
    gather_kernel<<<gat_blocks, 256, 0, stream>>>(csr, rptr, cnt, dinv, b2, Ts, A, n);

    readout_kernel<<<(n + 255) / 256, 256, 0, stream>>>(A, Wr0, br0, Wr1, br1,
                                                        batch, gsum, gcnt, n);
    pool_fin_kernel<<<(ng + 255) / 256, 256, 0, stream>>>(gsum, gcnt, out, ng);
}

// Round 5
// 597.071 us; speedup vs baseline: 1.5766x; 1.5766x over previous
//
#include <hip/hip_runtime.h>

// ---------------------------------------------------------------------------
// Petri_GCN: 3x GCNConv(64->64) + MLP readout (64->32->1) + segment-mean pool
// All fp32 (abs threshold forbids bf16/MFMA; no fp32 MFMA on CDNA4).
// R1: CSR-by-dst (counting sort) + gather instead of atomic scatter.
// R2: readout wave-segmented atomics; gather 4x(16-lane x float4) layout.
// R3: count-only atomic pass; Ts=(X@W)*dinv epilogue; gather pure-write.
// R4: FIX gemm W-register residency: no __restrict__ on X/W/Ts (stores may
//     alias W reads -> compiler can't rematerialize W loads in the loop) +
//     __launch_bounds__(256,2) (allow 256 VGPR; R4 regression had VGPR=64,
//     W reloaded per row, FETCH 392MB, 201us vs ~60us in R2).
// ---------------------------------------------------------------------------

__global__ void cnt_kernel(const int* __restrict__ dst,
                           int* __restrict__ cnt, int ne) {
    int e = blockIdx.x * blockDim.x + threadIdx.x;
    if (e < ne) atomicAdd(&cnt[dst[e]], 1);
}

// --- 3-pass exclusive scan of cnt[] -> row_ptr[] ---------------------------
#define SCAN_B 256
__global__ void scan1_kernel(const int* __restrict__ cnt,
                             int* __restrict__ excl,
                             int* __restrict__ bsum, int n) {
    __shared__ int sh[SCAN_B];
    int i = blockIdx.x * SCAN_B + threadIdx.x;
    int c = (i < n) ? cnt[i] : 0;
    sh[threadIdx.x] = c;
    __syncthreads();
    for (int off = 1; off < SCAN_B; off <<= 1) {
        int v = (threadIdx.x >= off) ? sh[threadIdx.x - off] : 0;
        __syncthreads();
        sh[threadIdx.x] += v;
        __syncthreads();
    }
    if (i < n) excl[i] = sh[threadIdx.x] - c;
    if (threadIdx.x == SCAN_B - 1) bsum[blockIdx.x] = sh[threadIdx.x];
}

__global__ void scan2_kernel(int* __restrict__ bsum, int nb) {
    __shared__ int sh[512];
    int t = threadIdx.x;
    int v = (t < nb) ? bsum[t] : 0;
    sh[t] = v;
    __syncthreads();
    for (int off = 1; off < 512; off <<= 1) {
        int u = (t >= off) ? sh[t - off] : 0;
        __syncthreads();
        sh[t] += u;
        __syncthreads();
    }
    if (t < nb) bsum[t] = sh[t] - v;
}

__global__ void scan3_kernel(const int* __restrict__ excl,
                             const int* __restrict__ bsum,
                             int* __restrict__ rptr,
                             int* __restrict__ cursor, int n) {
    int i = blockIdx.x * SCAN_B + threadIdx.x;
    if (i < n) {
        int s = excl[i] + bsum[blockIdx.x];
        rptr[i] = s;
        cursor[i] = s;
    }
}

// Fill CSR with {src, raw_w} packed as int2 (one 8B write per edge).
__global__ void fill_kernel(const int* __restrict__ src,
                            const int* __restrict__ dst,
                            const float* __restrict__ ew,
                            int* __restrict__ cursor,
                            int2* __restrict__ csr, int ne) {
    int e = blockIdx.x * blockDim.x + threadIdx.x;
    if (e >= ne) return;
    int d = dst[e];
    int pos = atomicAdd(&cursor[d], 1);
    int2 v;
    v.x = src[e];
    v.y = __float_as_int(ew[e]);
    csr[pos] = v;
}

// deg[r] = sum of raw w over row r (+1 self-loop); dinv = 1/sqrt(deg).
__global__ void deg_row_kernel(const int2* __restrict__ csr,
                               const int* __restrict__ rptr,
                               const int* __restrict__ cnt,
                               float* __restrict__ dinv, int n) {
    int lane = threadIdx.x & 63;
    int wid  = (blockIdx.x * blockDim.x + threadIdx.x) >> 6;
    int sub  = lane >> 4;
    int k    = lane & 15;
    int r = wid * 4 + sub;
    if (r >= n) return;
    int start = rptr[r];
    int m = cnt[r];
    float s = 0.0f;
    for (int j = k; j < m; j += 16) s += __int_as_float(csr[start + j].y);
#pragma unroll
    for (int off = 1; off < 16; off <<= 1) s += __shfl_xor(s, off);
    if (k == 0) dinv[r] = 1.0f / sqrtf(s + 1.0f);
}

// One wave per row. Lane c holds W[:,c] in 64 VGPRs. X row read as uniform
// float4 broadcasts. Single store: Ts = act(X)@W * dinv[r].
// NO __restrict__ on X/W/Ts: the possible store->W aliasing pins the 64
// hoisted W loads in registers (compiler may not rematerialize them past
// stores). X aliases A across layers anyway (in-place).
template <bool RELU>
__global__ void __launch_bounds__(256, 2)
gemm_ts_kernel(const float* X, const float* W,
               const float* __restrict__ dinv,
               float* Ts, int n) {
    int lane = threadIdx.x & 63;
    int wid  = (blockIdx.x * blockDim.x + threadIdx.x) >> 6;
    int nw   = (gridDim.x * blockDim.x) >> 6;
    float wc[64];
#pragma unroll
    for (int k = 0; k < 64; ++k) wc[k] = W[k * 64 + lane];
    for (int r = wid; r < n; r += nw) {
        const float4* xr = (const float4*)(X + (size_t)r * 64);
        float acc = 0.0f;
#pragma unroll
        for (int k4 = 0; k4 < 16; ++k4) {
            float4 x4 = xr[k4];
            if (RELU) {
                x4.x = fmaxf(x4.x, 0.0f); x4.y = fmaxf(x4.y, 0.0f);
                x4.z = fmaxf(x4.z, 0.0f); x4.w = fmaxf(x4.w, 0.0f);
            }
            acc = fmaf(x4.x, wc[4 * k4 + 0], acc);
            acc = fmaf(x4.y, wc[4 * k4 + 1], acc);
            acc = fmaf(x4.z, wc[4 * k4 + 2], acc);
            acc = fmaf(x4.w, wc[4 * k4 + 3], acc);
        }
        Ts[(size_t)r * 64 + lane] = acc * dinv[r];
    }
}

// One wave per dst row. 4 subgroups of 16 lanes; subgroup handles every 4th
// edge; lane's float4 covers channels 4*cl..4*cl+3. One dwordx4 VMEM instr
// serves 4 edges. A[r] = dinv[r]*(sum + Ts[r]) + b  (pure write).
__global__ void gather_kernel(const int2* __restrict__ csr,
                              const int* __restrict__ rptr,
                              const int* __restrict__ cnt,
                              const float* __restrict__ dinv,
                              const float* __restrict__ b,
                              const float* __restrict__ Ts,
                              float* __restrict__ A, int n) {
    int lane = threadIdx.x & 63;
    int r = (int)(((size_t)blockIdx.x * blockDim.x + threadIdx.x) >> 6);
    if (r >= n) return;
    int sub = lane >> 4;          // 0..3: edge subgroup
    int cl  = lane & 15;          // channel quad
    int start = rptr[r];
    int m = cnt[r];
    float4 a0 = {0.f, 0.f, 0.f, 0.f};
    float4 a1 = {0.f, 0.f, 0.f, 0.f};
    int j = sub;
    for (; j + 4 < m; j += 8) {
        int2 e0 = csr[start + j];
        int2 e1 = csr[start + j + 4];
        float w0 = __int_as_float(e0.y);
        float w1 = __int_as_float(e1.y);
        float4 t0 = *(const float4*)&Ts[(size_t)e0.x * 64 + cl * 4];
        float4 t1 = *(const float4*)&Ts[(size_t)e1.x * 64 + cl * 4];
        a0.x = fmaf(t0.x, w0, a0.x); a0.y = fmaf(t0.y, w0, a0.y);
        a0.z = fmaf(t0.z, w0, a0.z); a0.w = fmaf(t0.w, w0, a0.w);
        a1.x = fmaf(t1.x, w1, a1.x); a1.y = fmaf(t1.y, w1, a1.y);
        a1.z = fmaf(t1.z, w1, a1.z); a1.w = fmaf(t1.w, w1, a1.w);
    }
    if (j < m) {
        int2 e0 = csr[start + j];
        float w0 = __int_as_float(e0.y);
        float4 t0 = *(const float4*)&Ts[(size_t)e0.x * 64 + cl * 4];
        a0.x = fmaf(t0.x, w0, a0.x); a0.y = fmaf(t0.y, w0, a0.y);
        a0.z = fmaf(t0.z, w0, a0.z); a0.w = fmaf(t0.w, w0, a0.w);
    }
    a0.x += a1.x; a0.y += a1.y; a0.z += a1.z; a0.w += a1.w;
#pragma unroll
    for (int off = 16; off < 64; off <<= 1) {
        a0.x += __shfl_xor(a0.x, off);
        a0.y += __shfl_xor(a0.y, off);
        a0.z += __shfl_xor(a0.z, off);
        a0.w += __shfl_xor(a0.w, off);
    }
    if (sub == 0) {
        float dv = dinv[r];
        float4 ts = *(const float4*)&Ts[(size_t)r * 64 + cl * 4];
        float4 bb = *(const float4*)&b[cl * 4];
        float4 o;
        o.x = fmaf(dv, a0.x + ts.x, bb.x);
        o.y = fmaf(dv, a0.y + ts.y, bb.y);
        o.z = fmaf(dv, a0.z + ts.z, bb.z);
        o.w = fmaf(dv, a0.w + ts.w, bb.w);
        *(float4*)&A[(size_t)r * 64 + cl * 4] = o;
    }
}

// Thread per node: sv = relu(h @ Wr0 + br0) @ Wr1 + br1.
// batch is sorted -> wave-segmented suffix reduction, heads do the atomics.
__global__ void readout_kernel(const float* __restrict__ H,
                               const float* __restrict__ Wr0,
                               const float* __restrict__ br0,
                               const float* __restrict__ Wr1,
                               const float* __restrict__ br1,
                               const int* __restrict__ batch,
                               float* __restrict__ gsum,
                               float* __restrict__ gcnt, int n) {
    __shared__ float Ws[64 * 32];
    __shared__ float w1s[32];
    for (int i = threadIdx.x; i < 64 * 32; i += blockDim.x) Ws[i] = Wr0[i];
    if (threadIdx.x < 32) w1s[threadIdx.x] = Wr1[threadIdx.x];
    __syncthreads();
    int r = blockIdx.x * blockDim.x + threadIdx.x;
    int lane = threadIdx.x & 63;
    float sv = 0.0f;
    int g = -1;
    if (r < n) {
        float h[64];
        const float4* hr = (const float4*)(H + (size_t)r * 64);
#pragma unroll
        for (int i = 0; i < 16; ++i) {
            float4 v = hr[i];
            h[4 * i + 0] = v.x; h[4 * i + 1] = v.y;
            h[4 * i + 2] = v.z; h[4 * i + 3] = v.w;
        }
        float ssum = 0.0f;
#pragma unroll 1
        for (int jg = 0; jg < 8; ++jg) {
            float a0 = br0[jg * 4 + 0], a1 = br0[jg * 4 + 1];
            float a2 = br0[jg * 4 + 2], a3 = br0[jg * 4 + 3];
#pragma unroll
            for (int k = 0; k < 64; ++k) {
                const float4 wv = *(const float4*)&Ws[k * 32 + jg * 4];
                a0 = fmaf(h[k], wv.x, a0);
                a1 = fmaf(h[k], wv.y, a1);
                a2 = fmaf(h[k], wv.z, a2);
                a3 = fmaf(h[k], wv.w, a3);
            }
            a0 = fmaxf(a0, 0.0f); a1 = fmaxf(a1, 0.0f);
            a2 = fmaxf(a2, 0.0f); a3 = fmaxf(a3, 0.0f);
            ssum += a0 * w1s[jg * 4 + 0] + a1 * w1s[jg * 4 + 1] +
                    a2 * w1s[jg * 4 + 2] + a3 * w1s[jg * 4 + 3];
        }
        sv = ssum + br1[0];
        g = batch[r];
    }
    float c = (r < n) ? 1.0f : 0.0f;
#pragma unroll
    for (int off = 1; off < 64; off <<= 1) {
        int   og = __shfl_down(g, off);
        float ov = __shfl_down(sv, off);
        float oc = __shfl_down(c, off);
        if ((lane + off) < 64 && og == g) { sv += ov; c += oc; }
    }
    int gprev = __shfl_up(g, 1);
    bool head = (lane == 0) || (gprev != g);
    if (head && g >= 0) {
        atomicAdd(&gsum[g], sv);
        atomicAdd(&gcnt[g], c);
    }
}

__global__ void pool_fin_kernel(const float* __restrict__ gsum,
                                const float* __restrict__ gcnt,
                                float* __restrict__ out, int ng) {
    int g = blockIdx.x * blockDim.x + threadIdx.x;
    if (g < ng) out[g] = gsum[g] / fmaxf(gcnt[g], 1.0f);
}

extern "C" void kernel_launch(void* const* d_in, const int* in_sizes, int n_in,
                              void* d_out, int out_size, void* d_ws, size_t ws_size,
                              hipStream_t stream) {
    const float* x    = (const float*)d_in[0];
    const int*   ei   = (const int*)d_in[1];
    const float* ew   = (const float*)d_in[2];
    const int*   batch= (const int*)d_in[3];
    const float* W0   = (const float*)d_in[4];
    const float* b0   = (const float*)d_in[5];
    const float* W1   = (const float*)d_in[6];
    const float* b1   = (const float*)d_in[7];
    const float* W2   = (const float*)d_in[8];
    const float* b2   = (const float*)d_in[9];
    const float* Wr0  = (const float*)d_in[10];
    const float* br0  = (const float*)d_in[11];
    const float* Wr1  = (const float*)d_in[12];
    const float* br1  = (const float*)d_in[13];
    float* out = (float*)d_out;

    int n  = in_sizes[0] / 64;   // 100000
    int ne = in_sizes[1] / 2;    // 1600000
    int ng = out_size;           // 256
    const int* srcv = ei;
    const int* dstv = ei + ne;

    char* ws = (char*)d_ws;
    size_t off = 0;
    auto alloc = [&](size_t bytes) {
        void* p = ws + off;
        off += (bytes + 255) & ~(size_t)255;
        return p;
    };
    float* Ts     = (float*)alloc((size_t)n * 64 * sizeof(float));
    float* A      = (float*)alloc((size_t)n * 64 * sizeof(float));
    float* dinv   = (float*)alloc((size_t)n * sizeof(float));
    int*   cnt    = (int*)alloc((size_t)n * sizeof(int));
    int*   excl   = (int*)alloc((size_t)n * sizeof(int));
    int*   rptr   = (int*)alloc((size_t)n * sizeof(int));
    int*   cursor = (int*)alloc((size_t)n * sizeof(int));
    int*   bsum   = (int*)alloc(512 * sizeof(int));
    int2*  csr    = (int2*)alloc((size_t)ne * sizeof(int2));
    float* gsum   = (float*)alloc((size_t)ng * sizeof(float));
    float* gcnt   = (float*)alloc((size_t)ng * sizeof(float));
    (void)ws_size;

    int nb = (n + SCAN_B - 1) / SCAN_B;   // 391 <= 512

    hipMemsetAsync(cnt, 0, (size_t)n * sizeof(int), stream);
    hipMemsetAsync(gsum, 0, (size_t)ng * sizeof(float), stream);
    hipMemsetAsync(gcnt, 0, (size_t)ng * sizeof(float), stream);

    cnt_kernel<<<(ne + 255) / 256, 256, 0, stream>>>(dstv, cnt, ne);
    scan1_kernel<<<nb, SCAN_B, 0, stream>>>(cnt, excl, bsum, n);
    scan2_kernel<<<1, 512, 0, stream>>>(bsum, nb);
    scan3_kernel<<<nb, SCAN_B, 0, stream>>>(excl, bsum, rptr, cursor, n);
    fill_kernel<<<(ne + 255) / 256, 256, 0, stream>>>(srcv, dstv, ew, cursor, csr, ne);
    deg_row_kernel<<<(n + 15) / 16, 256, 0, stream>>>(csr, rptr, cnt, dinv, n);

    const int gemm_blocks = 1024;
    unsigned gat_blocks = (unsigned)(((size_t)n * 64 + 255) / 256);

    gemm_ts_kernel<false><<<gemm_blocks, 256, 0, stream>>>(x, W0, dinv, Ts, n);
    gather_kernel<<<gat_blocks, 256, 0, stream>>>(csr, rptr, cnt, dinv, b0, Ts, A, n);

    gemm_ts_kernel<true><<<gemm_blocks, 256, 0, stream>>>(A, W1, dinv, Ts, n);
    gather_kernel<<<gat_blocks, 256, 0, stream>>>(csr, rptr, cnt, dinv, b1, Ts, A, n);

    gemm_ts_kernel<true><<<gemm_blocks, 256, 0, stream>>>(A, W2, dinv, Ts, n);
    gather_kernel<<<gat_blocks, 256, 0, stream>>>(csr, rptr, cnt, dinv, b2, Ts, A, n);

    readout_kernel<<<(n + 255) / 256, 256, 0, stream>>>(A, Wr0, br0, Wr1, br1,
                                                        batch, gsum, gcnt, n);
    pool_fin_kernel<<<(ng + 255) / 256, 256, 0, stream>>>(gsum, gcnt, out, ng);
}

// Round 6
// 467.496 us; speedup vs baseline: 2.0135x; 1.2772x over previous
//
#include <hip/hip_runtime.h>

// ---------------------------------------------------------------------------
// Petri_GCN: 3x GCNConv(64->64) + MLP readout (64->32->1) + segment-mean pool
// All fp32 (abs threshold forbids bf16/MFMA; no fp32 MFMA on CDNA4).
// R1: CSR-by-dst + gather instead of atomic scatter.
// R2: readout wave-segmented atomics; gather 4x(16-lane x float4) layout.
// R3: count-only atomic pass; Ts=(X@W)*dinv epilogue; gather pure-write.
// R4: gemm W-register residency: NO __restrict__ on X/W/Ts + launch_bounds
//     (256,2). (R4 regression: VGPR=64, W reloaded per row, FETCH 392MB.)
// R5: bucketed 2-phase CSR build. Old fill_kernel: 8B random scatter = 64B
//     HBM line per store (WRITE 100MB, 125us) + 1.6M contended atomics.
//     Now: 391 buckets of 256 nodes; scatterB writes dense per-WG runs;
//     bucket_build does per-node count/scan/scatter in LDS within an L2-hot
//     32KB window, and computes dinv (absorbs deg_row). No global cnt pass.
// ---------------------------------------------------------------------------

#define NBK 391          // ceil(100000/256) buckets; arrays padded to 512

// LDS histogram of dst>>8, merged to global.
__global__ void hist_kernel(const int* __restrict__ dst,
                            int* __restrict__ bcnt, int ne) {
    __shared__ int h[512];
    for (int i = threadIdx.x; i < 512; i += blockDim.x) h[i] = 0;
    __syncthreads();
    int stride = gridDim.x * blockDim.x;
    for (int e = blockIdx.x * blockDim.x + threadIdx.x; e < ne; e += stride)
        atomicAdd(&h[dst[e] >> 8], 1);
    __syncthreads();
    for (int i = threadIdx.x; i < 512; i += blockDim.x)
        if (h[i]) atomicAdd(&bcnt[i], h[i]);
}

// One block: exclusive scan of bucket counts -> bbase[0..nb], seed gcur.
__global__ void bscan_kernel(const int* __restrict__ bcnt,
                             int* __restrict__ bbase,
                             int* __restrict__ gcur, int nb, int ne) {
    __shared__ int sh[512];
    int t = threadIdx.x;
    int v = (t < nb) ? bcnt[t] : 0;
    sh[t] = v;
    __syncthreads();
    for (int off = 1; off < 512; off <<= 1) {
        int u = (t >= off) ? sh[t - off] : 0;
        __syncthreads();
        sh[t] += u;
        __syncthreads();
    }
    if (t < nb) {
        int e = sh[t] - v;
        bbase[t] = e;
        gcur[t] = e;
    }
    if (t == 0) bbase[nb] = ne;
}

// Redistribute edges into bucket regions. Per-WG: LDS chunk histogram,
// one global atomic per touched bucket reserves a dense run, LDS cursors
// place edges. packed = {(local8<<24)|src17, w}.
__global__ void scatterB_kernel(const int* __restrict__ src,
                                const int* __restrict__ dst,
                                const float* __restrict__ ew,
                                int* __restrict__ gcur,
                                int2* __restrict__ packed, int ne) {
    __shared__ int h[512];
    __shared__ int cur[512];
    int chunk = (ne + gridDim.x - 1) / gridDim.x;
    int e0 = blockIdx.x * chunk;
    int e1 = e0 + chunk; if (e1 > ne) e1 = ne;
    for (int i = threadIdx.x; i < 512; i += blockDim.x) h[i] = 0;
    __syncthreads();
    for (int e = e0 + threadIdx.x; e < e1; e += blockDim.x)
        atomicAdd(&h[dst[e] >> 8], 1);
    __syncthreads();
    for (int i = threadIdx.x; i < 512; i += blockDim.x)
        cur[i] = h[i] ? atomicAdd(&gcur[i], h[i]) : 0;
    __syncthreads();
    for (int e = e0 + threadIdx.x; e < e1; e += blockDim.x) {
        int d = dst[e];
        int pos = atomicAdd(&cur[d >> 8], 1);   // LDS atomic
        int2 v;
        v.x = ((d & 255) << 24) | src[e];       // src < 2^17, fits
        v.y = __float_as_int(ew[e]);
        packed[pos] = v;
    }
}

// One WG per bucket (256 nodes). Count per node in LDS, LDS scan -> rptr/cnt,
// scatter final CSR within the bucket's own window (L2-hot), then per-thread
// sequential row-sum of w -> dinv. No global atomics anywhere.
__global__ void bucket_build_kernel(const int2* __restrict__ packed,
                                    const int* __restrict__ bbase,
                                    int* __restrict__ rptr,
                                    int* __restrict__ cnt,
                                    float* __restrict__ dinv,
                                    int2* __restrict__ csr, int n) {
    __shared__ int cl[256];
    __shared__ int sc[256];
    __shared__ int cur[256];
    int b = blockIdx.x;
    int t = threadIdx.x;
    int node0 = b << 8;
    int nn = n - node0; if (nn > 256) nn = 256;
    int ebase = bbase[b];
    int m = bbase[b + 1] - ebase;
    cl[t] = 0;
    __syncthreads();
    for (int j = t; j < m; j += 256) {
        int local = ((unsigned)packed[ebase + j].x) >> 24;
        atomicAdd(&cl[local], 1);               // LDS atomic
    }
    __syncthreads();
    int c = cl[t];
    sc[t] = c;
    __syncthreads();
    for (int off = 1; off < 256; off <<= 1) {
        int u = (t >= off) ? sc[t - off] : 0;
        __syncthreads();
        sc[t] += u;
        __syncthreads();
    }
    int base = ebase + sc[t] - c;               // global CSR row start
    cur[t] = base;
    if (t < nn) {
        rptr[node0 + t] = base;
        cnt[node0 + t] = c;
    }
    __syncthreads();
    for (int j = t; j < m; j += 256) {
        int2 p = packed[ebase + j];
        int local = ((unsigned)p.x) >> 24;
        int pos = atomicAdd(&cur[local], 1);    // LDS atomic
        int2 v;
        v.x = p.x & 0x00FFFFFF;
        v.y = p.y;
        csr[pos] = v;
    }
    __syncthreads();
    if (t < nn) {
        float s = 0.0f;
        for (int j = base; j < base + c; ++j)
            s += __int_as_float(csr[j].y);
        dinv[node0 + t] = 1.0f / sqrtf(s + 1.0f);
    }
}

// One wave per row. Lane c holds W[:,c] in 64 VGPRs. X row read as uniform
// float4 broadcasts. Single store: Ts = act(X)@W * dinv[r].
// NO __restrict__ on X/W/Ts: possible store->W aliasing pins the 64 hoisted
// W loads in registers (R4 lesson). X aliases A across layers (in-place).
template <bool RELU>
__global__ void __launch_bounds__(256, 2)
gemm_ts_kernel(const float* X, const float* W,
               const float* __restrict__ dinv,
               float* Ts, int n) {
    int lane = threadIdx.x & 63;
    int wid  = (blockIdx.x * blockDim.x + threadIdx.x) >> 6;
    int nw   = (gridDim.x * blockDim.x) >> 6;
    float wc[64];
#pragma unroll
    for (int k = 0; k < 64; ++k) wc[k] = W[k * 64 + lane];
    for (int r = wid; r < n; r += nw) {
        const float4* xr = (const float4*)(X + (size_t)r * 64);
        float acc = 0.0f;
#pragma unroll
        for (int k4 = 0; k4 < 16; ++k4) {
            float4 x4 = xr[k4];
            if (RELU) {
                x4.x = fmaxf(x4.x, 0.0f); x4.y = fmaxf(x4.y, 0.0f);
                x4.z = fmaxf(x4.z, 0.0f); x4.w = fmaxf(x4.w, 0.0f);
            }
            acc = fmaf(x4.x, wc[4 * k4 + 0], acc);
            acc = fmaf(x4.y, wc[4 * k4 + 1], acc);
            acc = fmaf(x4.z, wc[4 * k4 + 2], acc);
            acc = fmaf(x4.w, wc[4 * k4 + 3], acc);
        }
        Ts[(size_t)r * 64 + lane] = acc * dinv[r];
    }
}

// One wave per dst row. 4 subgroups of 16 lanes; subgroup handles every 4th
// edge; lane's float4 covers channels 4*cl..4*cl+3. One dwordx4 VMEM instr
// serves 4 edges. A[r] = dinv[r]*(sum + Ts[r]) + b  (pure write).
__global__ void gather_kernel(const int2* __restrict__ csr,
                              const int* __restrict__ rptr,
                              const int* __restrict__ cnt,
                              const float* __restrict__ dinv,
                              const float* __restrict__ b,
                              const float* __restrict__ Ts,
                              float* __restrict__ A, int n) {
    int lane = threadIdx.x & 63;
    int r = (int)(((size_t)blockIdx.x * blockDim.x + threadIdx.x) >> 6);
    if (r >= n) return;
    int sub = lane >> 4;          // 0..3: edge subgroup
    int cl  = lane & 15;          // channel quad
    int start = rptr[r];
    int m = cnt[r];
    float4 a0 = {0.f, 0.f, 0.f, 0.f};
    float4 a1 = {0.f, 0.f, 0.f, 0.f};
    int j = sub;
    for (; j + 4 < m; j += 8) {
        int2 e0 = csr[start + j];
        int2 e1 = csr[start + j + 4];
        float w0 = __int_as_float(e0.y);
        float w1 = __int_as_float(e1.y);
        float4 t0 = *(const float4*)&Ts[(size_t)e0.x * 64 + cl * 4];
        float4 t1 = *(const float4*)&Ts[(size_t)e1.x * 64 + cl * 4];
        a0.x = fmaf(t0.x, w0, a0.x); a0.y = fmaf(t0.y, w0, a0.y);
        a0.z = fmaf(t0.z, w0, a0.z); a0.w = fmaf(t0.w, w0, a0.w);
        a1.x = fmaf(t1.x, w1, a1.x); a1.y = fmaf(t1.y, w1, a1.y);
        a1.z = fmaf(t1.z, w1, a1.z); a1.w = fmaf(t1.w, w1, a1.w);
    }
    if (j < m) {
        int2 e0 = csr[start + j];
        float w0 = __int_as_float(e0.y);
        float4 t0 = *(const float4*)&Ts[(size_t)e0.x * 64 + cl * 4];
        a0.x = fmaf(t0.x, w0, a0.x); a0.y = fmaf(t0.y, w0, a0.y);
        a0.z = fmaf(t0.z, w0, a0.z); a0.w = fmaf(t0.w, w0, a0.w);
    }
    a0.x += a1.x; a0.y += a1.y; a0.z += a1.z; a0.w += a1.w;
#pragma unroll
    for (int off = 16; off < 64; off <<= 1) {
        a0.x += __shfl_xor(a0.x, off);
        a0.y += __shfl_xor(a0.y, off);
        a0.z += __shfl_xor(a0.z, off);
        a0.w += __shfl_xor(a0.w, off);
    }
    if (sub == 0) {
        float dv = dinv[r];
        float4 ts = *(const float4*)&Ts[(size_t)r * 64 + cl * 4];
        float4 bb = *(const float4*)&b[cl * 4];
        float4 o;
        o.x = fmaf(dv, a0.x + ts.x, bb.x);
        o.y = fmaf(dv, a0.y + ts.y, bb.y);
        o.z = fmaf(dv, a0.z + ts.z, bb.z);
        o.w = fmaf(dv, a0.w + ts.w, bb.w);
        *(float4*)&A[(size_t)r * 64 + cl * 4] = o;
    }
}

// Thread per node: sv = relu(h @ Wr0 + br0) @ Wr1 + br1.
// batch is sorted -> wave-segmented suffix reduction, heads do the atomics.
__global__ void readout_kernel(const float* __restrict__ H,
                               const float* __restrict__ Wr0,
                               const float* __restrict__ br0,
                               const float* __restrict__ Wr1,
                               const float* __restrict__ br1,
                               const int* __restrict__ batch,
                               float* __restrict__ gsum,
                               float* __restrict__ gcnt, int n) {
    __shared__ float Ws[64 * 32];
    __shared__ float w1s[32];
    for (int i = threadIdx.x; i < 64 * 32; i += blockDim.x) Ws[i] = Wr0[i];
    if (threadIdx.x < 32) w1s[threadIdx.x] = Wr1[threadIdx.x];
    __syncthreads();
    int r = blockIdx.x * blockDim.x + threadIdx.x;
    int lane = threadIdx.x & 63;
    float sv = 0.0f;
    int g = -1;
    if (r < n) {
        float h[64];
        const float4* hr = (const float4*)(H + (size_t)r * 64);
#pragma unroll
        for (int i = 0; i < 16; ++i) {
            float4 v = hr[i];
            h[4 * i + 0] = v.x; h[4 * i + 1] = v.y;
            h[4 * i + 2] = v.z; h[4 * i + 3] = v.w;
        }
        float ssum = 0.0f;
#pragma unroll 1
        for (int jg = 0; jg < 8; ++jg) {
            float a0 = br0[jg * 4 + 0], a1 = br0[jg * 4 + 1];
            float a2 = br0[jg * 4 + 2], a3 = br0[jg * 4 + 3];
#pragma unroll
            for (int k = 0; k < 64; ++k) {
                const float4 wv = *(const float4*)&Ws[k * 32 + jg * 4];
                a0 = fmaf(h[k], wv.x, a0);
                a1 = fmaf(h[k], wv.y, a1);
                a2 = fmaf(h[k], wv.z, a2);
                a3 = fmaf(h[k], wv.w, a3);
            }
            a0 = fmaxf(a0, 0.0f); a1 = fmaxf(a1, 0.0f);
            a2 = fmaxf(a2, 0.0f); a3 = fmaxf(a3, 0.0f);
            ssum += a0 * w1s[jg * 4 + 0] + a1 * w1s[jg * 4 + 1] +
                    a2 * w1s[jg * 4 + 2] + a3 * w1s[jg * 4 + 3];
        }
        sv = ssum + br1[0];
        g = batch[r];
    }
    float c = (r < n) ? 1.0f : 0.0f;
#pragma unroll
    for (int off = 1; off < 64; off <<= 1) {
        int   og = __shfl_down(g, off);
        float ov = __shfl_down(sv, off);
        float oc = __shfl_down(c, off);
        if ((lane + off) < 64 && og == g) { sv += ov; c += oc; }
    }
    int gprev = __shfl_up(g, 1);
    bool head = (lane == 0) || (gprev != g);
    if (head && g >= 0) {
        atomicAdd(&gsum[g], sv);
        atomicAdd(&gcnt[g], c);
    }
}

__global__ void pool_fin_kernel(const float* __restrict__ gsum,
                                const float* __restrict__ gcnt,
                                float* __restrict__ out, int ng) {
    int g = blockIdx.x * blockDim.x + threadIdx.x;
    if (g < ng) out[g] = gsum[g] / fmaxf(gcnt[g], 1.0f);
}

extern "C" void kernel_launch(void* const* d_in, const int* in_sizes, int n_in,
                              void* d_out, int out_size, void* d_ws, size_t ws_size,
                              hipStream_t stream) {
    const float* x    = (const float*)d_in[0];
    const int*   ei   = (const int*)d_in[1];
    const float* ew   = (const float*)d_in[2];
    const int*   batch= (const int*)d_in[3];
    const float* W0   = (const float*)d_in[4];
    const float* b0   = (const float*)d_in[5];
    const float* W1   = (const float*)d_in[6];
    const float* b1   = (const float*)d_in[7];
    const float* W2   = (const float*)d_in[8];
    const float* b2   = (const float*)d_in[9];
    const float* Wr0  = (const float*)d_in[10];
    const float* br0  = (const float*)d_in[11];
    const float* Wr1  = (const float*)d_in[12];
    const float* br1  = (const float*)d_in[13];
    float* out = (float*)d_out;

    int n  = in_sizes[0] / 64;   // 100000
    int ne = in_sizes[1] / 2;    // 1600000
    int ng = out_size;           // 256
    const int* srcv = ei;
    const int* dstv = ei + ne;
    int nbk = (n + 255) >> 8;    // 391

    char* ws = (char*)d_ws;
    size_t off = 0;
    auto alloc = [&](size_t bytes) {
        void* p = ws + off;
        off += (bytes + 255) & ~(size_t)255;
        return p;
    };
    float* Ts     = (float*)alloc((size_t)n * 64 * sizeof(float));
    float* A      = (float*)alloc((size_t)n * 64 * sizeof(float));
    float* dinv   = (float*)alloc((size_t)n * sizeof(float));
    int*   cnt    = (int*)alloc((size_t)n * sizeof(int));
    int*   rptr   = (int*)alloc((size_t)n * sizeof(int));
    int*   bcnt   = (int*)alloc(520 * sizeof(int));
    int*   bbase  = (int*)alloc(520 * sizeof(int));
    int*   gcur   = (int*)alloc(520 * sizeof(int));
    int2*  csr    = (int2*)alloc((size_t)ne * sizeof(int2));
    float* gsum   = (float*)alloc((size_t)ng * sizeof(float));
    float* gcnt   = (float*)alloc((size_t)ng * sizeof(float));
    // packed aliases Ts: consumed by bucket_build before first gemm writes Ts.
    int2*  packed = (int2*)Ts;
    (void)ws_size;

    hipMemsetAsync(bcnt, 0, 520 * sizeof(int), stream);
    hipMemsetAsync(gsum, 0, (size_t)ng * sizeof(float), stream);
    hipMemsetAsync(gcnt, 0, (size_t)ng * sizeof(float), stream);

    hist_kernel<<<256, 256, 0, stream>>>(dstv, bcnt, ne);
    bscan_kernel<<<1, 512, 0, stream>>>(bcnt, bbase, gcur, nbk, ne);
    scatterB_kernel<<<200, 256, 0, stream>>>(srcv, dstv, ew, gcur, packed, ne);
    bucket_build_kernel<<<nbk, 256, 0, stream>>>(packed, bbase, rptr, cnt,
                                                 dinv, csr, n);

    const int gemm_blocks = 1024;
    unsigned gat_blocks = (unsigned)(((size_t)n * 64 + 255) / 256);

    gemm_ts_kernel<false><<<gemm_blocks, 256, 0, stream>>>(x, W0, dinv, Ts, n);
    gather_kernel<<<gat_blocks, 256, 0, stream>>>(csr, rptr, cnt, dinv, b0, Ts, A, n);

    gemm_ts_kernel<true><<<gemm_blocks, 256, 0, stream>>>(A, W1, dinv, Ts, n);
    gather_kernel<<<gat_blocks, 256, 0, stream>>>(csr, rptr, cnt, dinv, b1, Ts, A, n);

    gemm_ts_kernel<true><<<gemm_blocks, 256, 0, stream>>>(A, W2, dinv, Ts, n);
    gather_kernel<<<gat_blocks, 256, 0, stream>>>(csr, rptr, cnt, dinv, b2, Ts, A, n);

    readout_kernel<<<(n + 255) / 256, 256, 0, stream>>>(A, Wr0, br0, Wr1, br1,
                                                        batch, gsum, gcnt, n);
    pool_fin_kernel<<<(ng + 255) / 256, 256, 0, stream>>>(gsum, gcnt, out, ng);
}